// Round 5
// baseline (128.622 us; speedup 1.0000x reference)
//
#include <hip/hip_runtime.h>

#define HD __device__ __forceinline__

typedef __attribute__((ext_vector_type(4))) float f32x4;
typedef __attribute__((ext_vector_type(8))) short bf16x8;

constexpr int B_ = 32, S_ = 128, DA = 256, DE = 256, K_ = 12, N_ = 128;
constexpr int W_ = S_ - K_;          // 116
constexpr int BW = B_ * W_;          // 3712 (= 29 * 128)

HD unsigned short f2bf(float f) {
    unsigned u = __float_as_uint(f);
    u += 0x7fffu + ((u >> 16) & 1u);          // round-to-nearest-even
    return (unsigned short)(u >> 16);
}

// ---- kernel 0: fused casts (A, Wp, E) + int64 detect, split by blockIdx ----
__global__ void k_prep(const float* __restrict__ A, const float* __restrict__ Wp,
                       const float* __restrict__ E, const unsigned int* __restrict__ idx,
                       unsigned short* __restrict__ Abf, unsigned short* __restrict__ Wpbf,
                       unsigned short* __restrict__ Ebf, unsigned int* __restrict__ flag) {
    int bx = blockIdx.x;
    const float* src; unsigned short* dst; int base;
    if (bx < 1024)      { src = A;  dst = Abf;  base = bx; }
    else if (bx < 1792) { src = Wp; dst = Wpbf; base = bx - 1024; }
    else if (bx < 2816) { src = E;  dst = Ebf;  base = bx - 1792; }
    else {
        __shared__ int anyNZ;
        if (threadIdx.x == 0) anyNZ = 0;
        __syncthreads();
        int nz = 0;
        for (int i = threadIdx.x; i < 4096; i += 256) nz |= (idx[2 * i + 1] != 0u);
        if (nz) atomicOr(&anyNZ, 1);
        __syncthreads();
        if (threadIdx.x == 0) *flag = (anyNZ == 0) ? 1u : 0u;   // 1 => int64
        return;
    }
    int i = base * 256 + threadIdx.x;
    float4 v = ((const float4*)src)[i];
    ushort4 o;
    o.x = f2bf(v.x); o.y = f2bf(v.y); o.z = f2bf(v.z); o.w = f2bf(v.w);
    ((ushort4*)dst)[i] = o;
}

// ---- kernel 2: locC[m][k][e] = sum_a C[m][a] * Wp[k][e][a], bf16 MFMA, 128x128 tile ----
__global__ __launch_bounds__(256) void k_locc(const unsigned short* __restrict__ Abf,
                                              const unsigned short* __restrict__ Wpbf,
                                              unsigned short* __restrict__ locC) {
    int bx = blockIdx.x;
    int k  = bx / 58;
    int r  = bx % 58;
    int mt = r >> 1;
    int et = r & 1;

    __shared__ unsigned short As[128][40];
    __shared__ unsigned short Bs[128][40];

    int tid  = threadIdx.x;
    int lane = tid & 63;
    int wid  = tid >> 6;
    int wr   = wid >> 1, wc = wid & 1;
    int l15  = lane & 15, lk = lane >> 4;

    f32x4 acc[4][4] = {};

    int srow = tid >> 1, spart = tid & 1;
    int m  = mt * 128 + srow;
    int bb = m / W_, ww = m - bb * W_;
    const unsigned short* aSrc = Abf + ((bb * S_ + ww) * DA) + spart * 16;
    const unsigned short* bSrc = Wpbf + ((k * DE + et * 128 + srow) * DA) + spart * 16;

    for (int c = 0; c < 8; ++c) {
        uint4 av0 = ((const uint4*)(aSrc + c * 32))[0];
        uint4 av1 = ((const uint4*)(aSrc + c * 32))[1];
        uint4 bv0 = ((const uint4*)(bSrc + c * 32))[0];
        uint4 bv1 = ((const uint4*)(bSrc + c * 32))[1];
        __syncthreads();
        ((uint4*)&As[srow][spart * 16])[0]     = av0;
        ((uint4*)&As[srow][spart * 16 + 8])[0] = av1;
        ((uint4*)&Bs[srow][spart * 16])[0]     = bv0;
        ((uint4*)&Bs[srow][spart * 16 + 8])[0] = bv1;
        __syncthreads();
        bf16x8 af[4], bfv[4];
        #pragma unroll
        for (int f = 0; f < 4; ++f) {
            af[f]  = *(const bf16x8*)&As[wr * 64 + f * 16 + l15][lk * 8];
            bfv[f] = *(const bf16x8*)&Bs[wc * 64 + f * 16 + l15][lk * 8];
        }
        #pragma unroll
        for (int fi = 0; fi < 4; ++fi)
            #pragma unroll
            for (int fj = 0; fj < 4; ++fj)
                acc[fi][fj] = __builtin_amdgcn_mfma_f32_16x16x32_bf16(af[fi], bfv[fj], acc[fi][fj], 0, 0, 0);
    }

    #pragma unroll
    for (int fi = 0; fi < 4; ++fi) {
        #pragma unroll
        for (int fj = 0; fj < 4; ++fj) {
            f32x4 v = acc[fi][fj];
            int eOut = et * 128 + wc * 64 + fj * 16 + l15;
            #pragma unroll
            for (int rr = 0; rr < 4; ++rr) {
                int mOut = mt * 128 + wr * 64 + fi * 16 + lk * 4 + rr;
                locC[(mOut * K_ + k) * DE + eOut] = f2bf(v[rr]);
            }
        }
    }
}

// ---- kernel 3: MFMA score + in-register LSE. 2 waves per pair (e-split), 2 pairs/block ----
// S[k][col] = (1/e) * sum_e locC[p][k][e] * Ebf[row(col)][e]; cols 0..127 negs,
// col 128+k = pos for k. D layout: col = lane&15, row(k) = (lane>>4)*4 + reg.
__global__ __launch_bounds__(256) void k_score(const unsigned short* __restrict__ Ebf,
                                               const unsigned int* __restrict__ idxRaw,
                                               const unsigned short* __restrict__ locC,
                                               const unsigned int* __restrict__ flag,
                                               float* __restrict__ partial) {
    __shared__ float xch[2][36][64];     // 18 KB, lane-contiguous (conflict-free)

    int tid  = threadIdx.x;
    int lane = tid & 63;
    int wid  = tid >> 6;
    int pl   = wid >> 1;                 // pair within block
    int eh   = wid & 1;                  // e-half this wave owns
    int l15  = lane & 15, lk = lane >> 4;
    int p    = blockIdx.x * 2 + pl;      // pair index < 3712
    int b    = p / W_, w = p - b * W_;

    bool i64 = (*flag != 0u);

    // gather rows for all 9 col-groups (independent loads, issued upfront)
    int rows[9];
    #pragma unroll
    for (int nf = 0; nf < 9; ++nf) {
        int col = nf * 16 + l15;
        if (col < N_) {
            int fi = (b * N_ + col) * W_ + w;
            rows[nf] = i64 ? (int)idxRaw[2 * fi] : (int)idxRaw[fi];
        } else {
            int j = col - N_;
            rows[nf] = b * S_ + ((j < K_) ? (w + j + 1) : 0);
        }
    }

    // A fragments: locC[p][k=l15][e-half], rows k>=12 zeroed; 4 K-steps of 32
    bf16x8 af[4];
    const unsigned short* aBase = locC + ((size_t)p * K_ + l15) * DE + eh * 128 + lk * 8;
    #pragma unroll
    for (int ks = 0; ks < 4; ++ks) {
        bf16x8 a = {};
        if (l15 < K_) a = *(const bf16x8*)(aBase + ks * 32);
        af[ks] = a;
    }

    f32x4 accs[9];
    #pragma unroll
    for (int nf = 0; nf < 9; ++nf) {
        const unsigned short* bBase = Ebf + (size_t)rows[nf] * DE + eh * 128 + lk * 8;
        f32x4 acc = {};
        #pragma unroll
        for (int ks = 0; ks < 4; ++ks) {
            bf16x8 bfv = *(const bf16x8*)(bBase + ks * 32);
            acc = __builtin_amdgcn_mfma_f32_16x16x32_bf16(af[ks], bfv, acc, 0, 0, 0);
        }
        accs[nf] = acc;
    }

    // combine the two e-halves through LDS
    if (eh == 1) {
        #pragma unroll
        for (int nf = 0; nf < 9; ++nf)
            #pragma unroll
            for (int rr = 0; rr < 4; ++rr)
                xch[pl][nf * 4 + rr][lane] = accs[nf][rr];
    }
    __syncthreads();
    if (eh == 1) return;

    #pragma unroll
    for (int nf = 0; nf < 9; ++nf)
        #pragma unroll
        for (int rr = 0; rr < 4; ++rr)
            accs[nf][rr] += xch[pl][nf * 4 + rr][lane];

    constexpr float inv_e = 1.0f / 256.0f;

    // raw-max over the 8 neg groups (this lane's col slice), then 16-lane col-reduce
    float m0[4], s0[4];
    #pragma unroll
    for (int rr = 0; rr < 4; ++rr) {
        float mx = accs[0][rr];
        #pragma unroll
        for (int nf = 1; nf < 8; ++nf) mx = fmaxf(mx, accs[nf][rr]);
        m0[rr] = mx;
    }
    #pragma unroll
    for (int off = 1; off < 16; off <<= 1)
        #pragma unroll
        for (int rr = 0; rr < 4; ++rr) m0[rr] = fmaxf(m0[rr], __shfl_xor(m0[rr], off));

    #pragma unroll
    for (int rr = 0; rr < 4; ++rr) {
        float s = 0.f;
        #pragma unroll
        for (int nf = 0; nf < 8; ++nf) s += __expf((accs[nf][rr] - m0[rr]) * inv_e);
        s0[rr] = s;
    }
    #pragma unroll
    for (int off = 1; off < 16; off <<= 1)
        #pragma unroll
        for (int rr = 0; rr < 4; ++rr) s0[rr] += __shfl_xor(s0[rr], off);

    // lanes with l15 = k (<12) and lk = k>>2 hold pos score in accs[8][k&3]
    if (l15 < K_ && lk == (l15 >> 2)) {
        int k = l15;
        #pragma unroll
        for (int rr = 0; rr < 4; ++rr) {
            if ((k & 3) == rr) {
                float ps   = accs[8][rr] * inv_e;
                float mneg = m0[rr] * inv_e;
                float M    = fmaxf(mneg, ps);
                float tot  = s0[rr] * __expf(mneg - M) + __expf(ps - M);
                partial[k * BW + p]        = M + __logf(tot) - ps;       // loss term
                partial[(12 + k) * BW + p] = (ps >= mneg) ? 1.0f : 0.0f; // argmax==0
            }
        }
    }
}

// ---- kernel 4: final mean over 3712 pairs, float32 outputs ----
__global__ void k_reduce(const float* __restrict__ partial, float* __restrict__ out) {
    int o = blockIdx.x;                  // 0..23
    float s = 0.f;
    for (int i = threadIdx.x; i < BW; i += 256) s += partial[o * BW + i];
    #pragma unroll
    for (int off = 32; off > 0; off >>= 1) s += __shfl_xor(s, off);
    __shared__ float w4[4];
    if ((threadIdx.x & 63) == 0) w4[threadIdx.x >> 6] = s;
    __syncthreads();
    if (threadIdx.x == 0)
        out[o] = (w4[0] + w4[1] + w4[2] + w4[3]) * (1.0f / BW);
}

extern "C" void kernel_launch(void* const* d_in, const int* in_sizes, int n_in,
                              void* d_out, int out_size, void* d_ws, size_t ws_size,
                              hipStream_t stream) {
    const float* cFeat = (const float*)d_in[0];
    const float* E     = (const float*)d_in[1];
    const float* Wp    = (const float*)d_in[2];
    const unsigned int* idxRaw = (const unsigned int*)d_in[3];

    char* ws = (char*)d_ws;
    unsigned short* locC    = (unsigned short*)(ws);             // 22,806,528 B
    unsigned short* Abf     = (unsigned short*)(ws + 22806528);  //  2,097,152 B
    unsigned short* Wpbf    = (unsigned short*)(ws + 24903680);  //  1,572,864 B
    float*          partial = (float*)        (ws + 26476544);   //    356,352 B
    unsigned int*   flag    = (unsigned int*) (ws + 26832896);   //        128 B
    unsigned short* Ebf     = (unsigned short*)(ws + 26833024);  //  2,097,152 B

    k_prep<<<2817, 256, 0, stream>>>(cFeat, Wp, E, idxRaw, Abf, Wpbf, Ebf, flag);
    k_locc<<<12 * 58, 256, 0, stream>>>(Abf, Wpbf, locC);
    k_score<<<BW / 2, 256, 0, stream>>>(Ebf, idxRaw, locC, flag, partial);
    k_reduce<<<24, 256, 0, stream>>>(partial, (float*)d_out);
}